// Round 1
// baseline (167.570 us; speedup 1.0000x reference)
//
#include <hip/hip_runtime.h>
#include <math.h>

#define KDIM 8192
#define BATCH 512
#define PDIM 4096

// ---------------------------------------------------------------------------
// Kernel 1: per batch row -> softmax (unnormalized) + A = sum_k e_k q_k q_k^T
// Writes 12 floats per batch: [sum_e, A00,A01,A02,A03,A11,A12,A13,A22,A23,A33, pad]
// ---------------------------------------------------------------------------
__global__ __launch_bounds__(256) void k_softmax_accum(
    const float* __restrict__ sep, const float* __restrict__ ohm,
    float* __restrict__ Abuf)
{
    __shared__ float srow[KDIM];   // 32 KB
    __shared__ float red[64];
    const int b    = blockIdx.x;
    const int tid  = threadIdx.x;
    const int lane = tid & 63, wave = tid >> 6;

    // stage row into LDS, track local max (coalesced float4)
    const float4* row4  = (const float4*)(sep + (size_t)b * KDIM);
    float4*       srow4 = (float4*)srow;
    float mx = -INFINITY;
    for (int i = tid; i < KDIM / 4; i += 256) {
        float4 v = row4[i];
        srow4[i] = v;
        mx = fmaxf(mx, fmaxf(fmaxf(v.x, v.y), fmaxf(v.z, v.w)));
    }
    #pragma unroll
    for (int off = 32; off > 0; off >>= 1)
        mx = fmaxf(mx, __shfl_down(mx, off, 64));
    if (lane == 0) red[wave] = mx;
    __syncthreads();
    if (tid == 0) red[0] = fmaxf(fmaxf(red[0], red[1]), fmaxf(red[2], red[3]));
    __syncthreads();
    mx = red[0];

    float acc[11];
    #pragma unroll
    for (int i = 0; i < 11; i++) acc[i] = 0.f;

    // one coalesced pass over the quaternion row (16 B/lane)
    const float4* q4 = (const float4*)(ohm + (size_t)b * KDIM * 4);
    for (int k = tid; k < KDIM; k += 256) {
        float4 q = q4[k];
        float e  = __expf(srow[k] - mx);
        float ex = e * q.x, ey = e * q.y, ez = e * q.z, ew = e * q.w;
        acc[0]  += e;
        acc[1]  += ex * q.x; acc[2] += ex * q.y; acc[3] += ex * q.z; acc[4] += ex * q.w;
        acc[5]  += ey * q.y; acc[6] += ey * q.z; acc[7] += ey * q.w;
        acc[8]  += ez * q.z; acc[9] += ez * q.w;
        acc[10] += ew * q.w;
    }

    __syncthreads();   // red[] reuse
    #pragma unroll
    for (int i = 0; i < 11; i++) {
        float s = acc[i];
        #pragma unroll
        for (int off = 32; off > 0; off >>= 1)
            s += __shfl_down(s, off, 64);
        if (lane == 0) red[wave * 11 + i] = s;
    }
    __syncthreads();
    if (tid < 11)
        Abuf[b * 12 + tid] = red[tid] + red[11 + tid] + red[22 + tid] + red[33 + tid];
}

// ---------------------------------------------------------------------------
// Kernel 2: per batch -> fp64 Jacobi eigensolve of 4x4, top eigenvector ->
// rotation matrix; also rotation matrix of gt. Writes 18 floats per batch.
// ---------------------------------------------------------------------------
__global__ void k_eig(const float* __restrict__ Abuf, const float* __restrict__ gt,
                      float* __restrict__ Rbuf)
{
    int b = blockIdx.x * blockDim.x + threadIdx.x;
    if (b >= BATCH) return;
    const float* a = Abuf + b * 12;
    double inv = 1.0 / (double)a[0];
    double A[4][4];
    A[0][0] = a[1] * inv; A[0][1] = a[2] * inv; A[0][2] = a[3] * inv; A[0][3] = a[4] * inv;
    A[1][1] = a[5] * inv; A[1][2] = a[6] * inv; A[1][3] = a[7] * inv;
    A[2][2] = a[8] * inv; A[2][3] = a[9] * inv; A[3][3] = a[10] * inv;
    A[1][0] = A[0][1]; A[2][0] = A[0][2]; A[3][0] = A[0][3];
    A[2][1] = A[1][2]; A[3][1] = A[1][3]; A[3][2] = A[2][3];

    double V[4][4];
    for (int i = 0; i < 4; i++)
        for (int j = 0; j < 4; j++) V[i][j] = (i == j) ? 1.0 : 0.0;

    for (int sweep = 0; sweep < 15; ++sweep) {
        double off = A[0][1]*A[0][1] + A[0][2]*A[0][2] + A[0][3]*A[0][3]
                   + A[1][2]*A[1][2] + A[1][3]*A[1][3] + A[2][3]*A[2][3];
        if (off < 1e-26) break;
        for (int p = 0; p < 3; p++) for (int q = p + 1; q < 4; q++) {
            double apq = A[p][q];
            if (fabs(apq) < 1e-30) continue;
            double theta = (A[q][q] - A[p][p]) / (2.0 * apq);
            double t = copysign(1.0, theta) / (fabs(theta) + sqrt(theta * theta + 1.0));
            double c = 1.0 / sqrt(t * t + 1.0);
            double s = t * c;
            for (int i = 0; i < 4; i++) {
                double aip = A[i][p], aiq = A[i][q];
                A[i][p] = c * aip - s * aiq;
                A[i][q] = s * aip + c * aiq;
            }
            for (int i = 0; i < 4; i++) {
                double api = A[p][i], aqi = A[q][i];
                A[p][i] = c * api - s * aqi;
                A[q][i] = s * api + c * aqi;
            }
            for (int i = 0; i < 4; i++) {
                double vip = V[i][p], viq = V[i][q];
                V[i][p] = c * vip - s * viq;
                V[i][q] = s * vip + c * viq;
            }
        }
    }
    int best = 0;
    for (int j = 1; j < 4; j++) if (A[j][j] > A[best][best]) best = j;
    double qr = V[0][best], qi = V[1][best], qj = V[2][best], qk = V[3][best];
    double two_s = 2.0 / (qr*qr + qi*qi + qj*qj + qk*qk);

    float* R = Rbuf + b * 18;
    // rm_pred (row-major 3x3), sign of eigenvector irrelevant (even in q)
    R[0] = (float)(1.0 - two_s * (qj*qj + qk*qk));
    R[1] = (float)(two_s * (qi*qj - qk*qr));
    R[2] = (float)(two_s * (qi*qk + qj*qr));
    R[3] = (float)(two_s * (qi*qj + qk*qr));
    R[4] = (float)(1.0 - two_s * (qi*qi + qk*qk));
    R[5] = (float)(two_s * (qj*qk - qi*qr));
    R[6] = (float)(two_s * (qi*qk - qj*qr));
    R[7] = (float)(two_s * (qj*qk + qi*qr));
    R[8] = (float)(1.0 - two_s * (qi*qi + qj*qj));
    // rm_gt
    double gr = gt[b*4+0], gi = gt[b*4+1], gj = gt[b*4+2], gk = gt[b*4+3];
    double gs = 2.0 / (gr*gr + gi*gi + gj*gj + gk*gk);
    R[9]  = (float)(1.0 - gs * (gj*gj + gk*gk));
    R[10] = (float)(gs * (gi*gj - gk*gr));
    R[11] = (float)(gs * (gi*gk + gj*gr));
    R[12] = (float)(gs * (gi*gj + gk*gr));
    R[13] = (float)(1.0 - gs * (gi*gi + gk*gk));
    R[14] = (float)(gs * (gj*gk - gi*gr));
    R[15] = (float)(gs * (gi*gk - gj*gr));
    R[16] = (float)(gs * (gj*gk + gi*gr));
    R[17] = (float)(1.0 - gs * (gi*gi + gj*gj));
}

// ---------------------------------------------------------------------------
// Kernel 3: rotate points by both matrices, accumulate ||diff|| per block.
// 2048 blocks x 256 threads, 4 points/thread (3 contiguous float4 per thread).
// ---------------------------------------------------------------------------
__global__ __launch_bounds__(256) void k_points(
    const float* __restrict__ point, const float* __restrict__ Rbuf,
    float* __restrict__ partial)
{
    const int blk   = blockIdx.x;
    const int b     = blk >> 2;      // batch
    const int chunk = blk & 3;       // quarter of the 4096 points
    const int tid   = threadIdx.x;
    const int lane  = tid & 63, wave = tid >> 6;
    __shared__ float red[4];

    const float* R = Rbuf + b * 18;
    float rp[9], rg[9];
    #pragma unroll
    for (int i = 0; i < 9; i++) { rp[i] = R[i]; rg[i] = R[9 + i]; }

    const float4* base = (const float4*)(point + ((size_t)b * PDIM + chunk * 1024) * 3);
    float4 v0 = base[tid * 3 + 0];
    float4 v1 = base[tid * 3 + 1];
    float4 v2 = base[tid * 3 + 2];
    float px[4] = { v0.x, v0.w, v1.z, v2.y };
    float py[4] = { v0.y, v1.x, v1.w, v2.z };
    float pz[4] = { v0.z, v1.y, v2.x, v2.w };

    float sum = 0.f;
    #pragma unroll
    for (int t = 0; t < 4; t++) {
        float x = px[t], y = py[t], z = pz[t];
        float ax = x*rp[0] + y*rp[3] + z*rp[6];
        float ay = x*rp[1] + y*rp[4] + z*rp[7];
        float az = x*rp[2] + y*rp[5] + z*rp[8];
        float bx = x*rg[0] + y*rg[3] + z*rg[6];
        float by = x*rg[1] + y*rg[4] + z*rg[7];
        float bz = x*rg[2] + y*rg[5] + z*rg[8];
        float dx = ax - bx, dy = ay - by, dz = az - bz;
        sum += sqrtf(dx*dx + dy*dy + dz*dz);
    }
    #pragma unroll
    for (int off = 32; off > 0; off >>= 1)
        sum += __shfl_down(sum, off, 64);
    if (lane == 0) red[wave] = sum;
    __syncthreads();
    if (tid == 0) partial[blk] = red[0] + red[1] + red[2] + red[3];
}

// ---------------------------------------------------------------------------
// Kernel 4: reduce 2048 partials in fp64, write mean.
// ---------------------------------------------------------------------------
__global__ __launch_bounds__(256) void k_final(
    const float* __restrict__ partial, float* __restrict__ out)
{
    const int tid  = threadIdx.x;
    const int lane = tid & 63, wave = tid >> 6;
    __shared__ double red[4];
    double s = 0.0;
    for (int i = tid; i < 2048; i += 256) s += (double)partial[i];
    #pragma unroll
    for (int off = 32; off > 0; off >>= 1)
        s += __shfl_down(s, off, 64);
    if (lane == 0) red[wave] = s;
    __syncthreads();
    if (tid == 0)
        out[0] = (float)((red[0] + red[1] + red[2] + red[3]) /
                         (double)((size_t)BATCH * PDIM));
}

extern "C" void kernel_launch(void* const* d_in, const int* in_sizes, int n_in,
                              void* d_out, int out_size, void* d_ws, size_t ws_size,
                              hipStream_t stream)
{
    const float* sep   = (const float*)d_in[0];   // (512, 8192)
    const float* ohm   = (const float*)d_in[1];   // (512, 8192, 4)
    const float* gt    = (const float*)d_in[2];   // (512, 4)
    const float* point = (const float*)d_in[3];   // (512, 4096, 3)
    float* out = (float*)d_out;

    float* Abuf = (float*)d_ws;            // 512*12 floats
    float* Rbuf = Abuf + BATCH * 12;       // 512*18 floats
    float* Pbuf = Rbuf + BATCH * 18;       // 2048 floats

    k_softmax_accum<<<BATCH, 256, 0, stream>>>(sep, ohm, Abuf);
    k_eig<<<2, 256, 0, stream>>>(Abuf, gt, Rbuf);
    k_points<<<2048, 256, 0, stream>>>(point, Rbuf, Pbuf);
    k_final<<<1, 256, 0, stream>>>(Pbuf, out);
}

// Round 2
// 150.247 us; speedup vs baseline: 1.1153x; 1.1153x over previous
//
#include <hip/hip_runtime.h>
#include <math.h>

#define KDIM 8192
#define BATCH 512
#define PDIM 4096
#define CHUNK 2048      // k-entries per block in stage 1 (4 chunks per batch)

// ---------------------------------------------------------------------------
// Kernel 1: flash-style partial softmax-weighted outer-product accumulation.
// Grid: BATCH*4 blocks x 256 threads. Block (b, c) handles k in [c*2048, ...).
// Writes 12 floats per chunk: [sum_e, A00,A01,A02,A03,A11,A12,A13,A22,A23,A33, mx]
// using the CHUNK-LOCAL max as the softmax shift (rescaled at combine time).
// ---------------------------------------------------------------------------
__global__ __launch_bounds__(256) void k_partial(
    const float* __restrict__ sep, const float* __restrict__ ohm,
    float* __restrict__ Cbuf)
{
    __shared__ float ss[CHUNK];   // 8 KB
    __shared__ float red[64];
    const int blk  = blockIdx.x;
    const int b    = blk >> 2;
    const int c    = blk & 3;
    const int tid  = threadIdx.x;
    const int lane = tid & 63, wave = tid >> 6;

    // stage chunk of sep into LDS (float4, coalesced), track local max
    const float4* s4  = (const float4*)(sep + (size_t)b * KDIM + c * CHUNK);
    float4*       ss4 = (float4*)ss;
    float mx = -INFINITY;
    #pragma unroll
    for (int i = 0; i < CHUNK / 4 / 256; i++) {
        float4 v = s4[tid + i * 256];
        ss4[tid + i * 256] = v;
        mx = fmaxf(mx, fmaxf(fmaxf(v.x, v.y), fmaxf(v.z, v.w)));
    }
    #pragma unroll
    for (int off = 32; off > 0; off >>= 1)
        mx = fmaxf(mx, __shfl_down(mx, off, 64));
    if (lane == 0) red[wave] = mx;
    __syncthreads();
    mx = fmaxf(fmaxf(red[0], red[1]), fmaxf(red[2], red[3]));

    float acc[11];
    #pragma unroll
    for (int i = 0; i < 11; i++) acc[i] = 0.f;

    // one coalesced pass over the quaternion chunk (16 B/lane, stride 256)
    const float4* q4 = (const float4*)(ohm + ((size_t)b * KDIM + c * CHUNK) * 4);
    #pragma unroll
    for (int j = 0; j < CHUNK / 256; j++) {
        const int k = j * 256 + tid;
        float4 q = q4[k];
        float e  = __expf(ss[k] - mx);
        float ex = e * q.x, ey = e * q.y, ez = e * q.z, ew = e * q.w;
        acc[0]  += e;
        acc[1]  += ex * q.x; acc[2] += ex * q.y; acc[3] += ex * q.z; acc[4] += ex * q.w;
        acc[5]  += ey * q.y; acc[6] += ey * q.z; acc[7] += ey * q.w;
        acc[8]  += ez * q.z; acc[9] += ez * q.w;
        acc[10] += ew * q.w;
    }

    __syncthreads();   // red[] reuse
    #pragma unroll
    for (int i = 0; i < 11; i++) {
        float s = acc[i];
        #pragma unroll
        for (int off = 32; off > 0; off >>= 1)
            s += __shfl_down(s, off, 64);
        if (lane == 0) red[wave * 12 + i] = s;
    }
    __syncthreads();
    if (tid < 11)
        Cbuf[blk * 12 + tid] = red[tid] + red[12 + tid] + red[24 + tid] + red[36 + tid];
    if (tid == 11)
        Cbuf[blk * 12 + 11] = mx;
}

// ---------------------------------------------------------------------------
// Kernel 2: per batch -> combine 4 chunks (flash rescale), fp64 Jacobi
// eigensolve of 4x4, top eigenvector -> D = R_pred - R_gt (9 floats/batch).
// Grid: 8 blocks x 64 threads (one thread per batch, spread across CUs).
// ---------------------------------------------------------------------------
__global__ __launch_bounds__(64) void k_eig(
    const float* __restrict__ Cbuf, const float* __restrict__ gt,
    float* __restrict__ Dbuf)
{
    int b = blockIdx.x * 64 + threadIdx.x;
    if (b >= BATCH) return;
    const float* C = Cbuf + b * 48;

    // global max over the 4 chunk maxima
    float mg = fmaxf(fmaxf(C[11], C[23]), fmaxf(C[35], C[47]));
    double sum_e = 0.0;
    double M[10];
    #pragma unroll
    for (int i = 0; i < 10; i++) M[i] = 0.0;
    #pragma unroll
    for (int c = 0; c < 4; c++) {
        const float* cc = C + c * 12;
        double f = exp((double)(cc[11] - mg));
        sum_e += f * (double)cc[0];
        #pragma unroll
        for (int i = 0; i < 10; i++) M[i] += f * (double)cc[1 + i];
    }
    double inv = 1.0 / sum_e;

    double A[4][4];
    A[0][0] = M[0]*inv; A[0][1] = M[1]*inv; A[0][2] = M[2]*inv; A[0][3] = M[3]*inv;
    A[1][1] = M[4]*inv; A[1][2] = M[5]*inv; A[1][3] = M[6]*inv;
    A[2][2] = M[7]*inv; A[2][3] = M[8]*inv; A[3][3] = M[9]*inv;
    A[1][0] = A[0][1]; A[2][0] = A[0][2]; A[3][0] = A[0][3];
    A[2][1] = A[1][2]; A[3][1] = A[1][3]; A[3][2] = A[2][3];

    double V[4][4];
    for (int i = 0; i < 4; i++)
        for (int j = 0; j < 4; j++) V[i][j] = (i == j) ? 1.0 : 0.0;

    for (int sweep = 0; sweep < 10; ++sweep) {
        double off = A[0][1]*A[0][1] + A[0][2]*A[0][2] + A[0][3]*A[0][3]
                   + A[1][2]*A[1][2] + A[1][3]*A[1][3] + A[2][3]*A[2][3];
        if (off < 1e-26) break;
        for (int p = 0; p < 3; p++) for (int q = p + 1; q < 4; q++) {
            double apq = A[p][q];
            if (fabs(apq) < 1e-30) continue;
            double theta = (A[q][q] - A[p][p]) / (2.0 * apq);
            double t = copysign(1.0, theta) / (fabs(theta) + sqrt(theta * theta + 1.0));
            double cth = 1.0 / sqrt(t * t + 1.0);
            double sth = t * cth;
            for (int i = 0; i < 4; i++) {
                double aip = A[i][p], aiq = A[i][q];
                A[i][p] = cth * aip - sth * aiq;
                A[i][q] = sth * aip + cth * aiq;
            }
            for (int i = 0; i < 4; i++) {
                double api = A[p][i], aqi = A[q][i];
                A[p][i] = cth * api - sth * aqi;
                A[q][i] = sth * api + cth * aqi;
            }
            for (int i = 0; i < 4; i++) {
                double vip = V[i][p], viq = V[i][q];
                V[i][p] = cth * vip - sth * viq;
                V[i][q] = sth * vip + cth * viq;
            }
        }
    }
    int best = 0;
    for (int j = 1; j < 4; j++) if (A[j][j] > A[best][best]) best = j;
    double qr = V[0][best], qi = V[1][best], qj = V[2][best], qk = V[3][best];
    double ps = 2.0 / (qr*qr + qi*qi + qj*qj + qk*qk);

    double gr = gt[b*4+0], gi = gt[b*4+1], gj = gt[b*4+2], gk = gt[b*4+3];
    double gs = 2.0 / (gr*gr + gi*gi + gj*gj + gk*gk);

    // D = R_pred - R_gt, row-major 3x3 (sign of eigenvector irrelevant)
    float* D = Dbuf + b * 9;
    D[0] = (float)((1.0 - ps*(qj*qj + qk*qk)) - (1.0 - gs*(gj*gj + gk*gk)));
    D[1] = (float)((ps*(qi*qj - qk*qr))       - (gs*(gi*gj - gk*gr)));
    D[2] = (float)((ps*(qi*qk + qj*qr))       - (gs*(gi*gk + gj*gr)));
    D[3] = (float)((ps*(qi*qj + qk*qr))       - (gs*(gi*gj + gk*gr)));
    D[4] = (float)((1.0 - ps*(qi*qi + qk*qk)) - (1.0 - gs*(gi*gi + gk*gk)));
    D[5] = (float)((ps*(qj*qk - qi*qr))       - (gs*(gj*gk - gi*gr)));
    D[6] = (float)((ps*(qi*qk - qj*qr))       - (gs*(gi*gk - gj*gr)));
    D[7] = (float)((ps*(qj*qk + qi*qr))       - (gs*(gj*gk + gi*gr)));
    D[8] = (float)((1.0 - ps*(qi*qi + qj*qj)) - (1.0 - gs*(gi*gi + gj*gj)));
}

// ---------------------------------------------------------------------------
// Kernel 3: ||p . D|| per point, accumulate per block.
// 2048 blocks x 256 threads, 4 points/thread (3 contiguous float4 per thread).
// ---------------------------------------------------------------------------
__global__ __launch_bounds__(256) void k_points(
    const float* __restrict__ point, const float* __restrict__ Dbuf,
    float* __restrict__ partial)
{
    const int blk   = blockIdx.x;
    const int b     = blk >> 2;
    const int chunk = blk & 3;
    const int tid   = threadIdx.x;
    const int lane  = tid & 63, wave = tid >> 6;
    __shared__ float red[4];

    const float* Dp = Dbuf + b * 9;
    float d[9];
    #pragma unroll
    for (int i = 0; i < 9; i++) d[i] = Dp[i];

    const float4* base = (const float4*)(point + ((size_t)b * PDIM + chunk * 1024) * 3);
    float4 v0 = base[tid * 3 + 0];
    float4 v1 = base[tid * 3 + 1];
    float4 v2 = base[tid * 3 + 2];
    float px[4] = { v0.x, v0.w, v1.z, v2.y };
    float py[4] = { v0.y, v1.x, v1.w, v2.z };
    float pz[4] = { v0.z, v1.y, v2.x, v2.w };

    float sum = 0.f;
    #pragma unroll
    for (int t = 0; t < 4; t++) {
        float x = px[t], y = py[t], z = pz[t];
        float dx = x*d[0] + y*d[3] + z*d[6];
        float dy = x*d[1] + y*d[4] + z*d[7];
        float dz = x*d[2] + y*d[5] + z*d[8];
        sum += sqrtf(dx*dx + dy*dy + dz*dz);
    }
    #pragma unroll
    for (int off = 32; off > 0; off >>= 1)
        sum += __shfl_down(sum, off, 64);
    if (lane == 0) red[wave] = sum;
    __syncthreads();
    if (tid == 0) partial[blk] = red[0] + red[1] + red[2] + red[3];
}

// ---------------------------------------------------------------------------
// Kernel 4: reduce 2048 partials in fp64, write mean.
// ---------------------------------------------------------------------------
__global__ __launch_bounds__(256) void k_final(
    const float* __restrict__ partial, float* __restrict__ out)
{
    const int tid  = threadIdx.x;
    const int lane = tid & 63, wave = tid >> 6;
    __shared__ double red[4];
    double s = 0.0;
    for (int i = tid; i < 2048; i += 256) s += (double)partial[i];
    #pragma unroll
    for (int off = 32; off > 0; off >>= 1)
        s += __shfl_down(s, off, 64);
    if (lane == 0) red[wave] = s;
    __syncthreads();
    if (tid == 0)
        out[0] = (float)((red[0] + red[1] + red[2] + red[3]) /
                         (double)((size_t)BATCH * PDIM));
}

extern "C" void kernel_launch(void* const* d_in, const int* in_sizes, int n_in,
                              void* d_out, int out_size, void* d_ws, size_t ws_size,
                              hipStream_t stream)
{
    const float* sep   = (const float*)d_in[0];   // (512, 8192)
    const float* ohm   = (const float*)d_in[1];   // (512, 8192, 4)
    const float* gt    = (const float*)d_in[2];   // (512, 4)
    const float* point = (const float*)d_in[3];   // (512, 4096, 3)
    float* out = (float*)d_out;

    float* Cbuf = (float*)d_ws;                 // 2048*12 floats
    float* Dbuf = Cbuf + BATCH * 4 * 12;        // 512*9 floats
    float* Pbuf = Dbuf + BATCH * 9;             // 2048 floats

    k_partial<<<BATCH * 4, 256, 0, stream>>>(sep, ohm, Cbuf);
    k_eig<<<8, 64, 0, stream>>>(Cbuf, gt, Dbuf);
    k_points<<<2048, 256, 0, stream>>>(point, Dbuf, Pbuf);
    k_final<<<1, 256, 0, stream>>>(Pbuf, out);
}

// Round 3
// 149.706 us; speedup vs baseline: 1.1193x; 1.0036x over previous
//
#include <hip/hip_runtime.h>
#include <math.h>

#define KDIM 8192
#define BATCH 512
#define PDIM 4096
#define CHUNK 2048      // k-entries per block in stage 1 (4 chunks per batch)

// ---------------------------------------------------------------------------
// Kernel 1: flash-style partial softmax-weighted outer-product accumulation.
// Grid: BATCH*4 blocks x 256 threads. Block (b, c) handles k in [c*2048, ...).
// Writes 12 floats per chunk: [sum_e, A00..A33 (10 upper-tri), mx]
// using the CHUNK-LOCAL max as the softmax shift (rescaled at combine time).
// ---------------------------------------------------------------------------
__global__ __launch_bounds__(256) void k_partial(
    const float* __restrict__ sep, const float* __restrict__ ohm,
    float* __restrict__ Cbuf)
{
    __shared__ float ss[CHUNK];   // 8 KB
    __shared__ float red[64];
    const int blk  = blockIdx.x;
    const int b    = blk >> 2;
    const int c    = blk & 3;
    const int tid  = threadIdx.x;
    const int lane = tid & 63, wave = tid >> 6;

    const float4* s4  = (const float4*)(sep + (size_t)b * KDIM + c * CHUNK);
    float4*       ss4 = (float4*)ss;
    float mx = -INFINITY;
    #pragma unroll
    for (int i = 0; i < CHUNK / 4 / 256; i++) {
        float4 v = s4[tid + i * 256];
        ss4[tid + i * 256] = v;
        mx = fmaxf(mx, fmaxf(fmaxf(v.x, v.y), fmaxf(v.z, v.w)));
    }
    #pragma unroll
    for (int off = 32; off > 0; off >>= 1)
        mx = fmaxf(mx, __shfl_down(mx, off, 64));
    if (lane == 0) red[wave] = mx;
    __syncthreads();
    mx = fmaxf(fmaxf(red[0], red[1]), fmaxf(red[2], red[3]));

    float acc[11];
    #pragma unroll
    for (int i = 0; i < 11; i++) acc[i] = 0.f;

    const float4* q4 = (const float4*)(ohm + ((size_t)b * KDIM + c * CHUNK) * 4);
    #pragma unroll
    for (int j = 0; j < CHUNK / 256; j++) {
        const int k = j * 256 + tid;
        float4 q = q4[k];
        float e  = __expf(ss[k] - mx);
        float ex = e * q.x, ey = e * q.y, ez = e * q.z, ew = e * q.w;
        acc[0]  += e;
        acc[1]  += ex * q.x; acc[2] += ex * q.y; acc[3] += ex * q.z; acc[4] += ex * q.w;
        acc[5]  += ey * q.y; acc[6] += ey * q.z; acc[7] += ey * q.w;
        acc[8]  += ez * q.z; acc[9] += ez * q.w;
        acc[10] += ew * q.w;
    }

    __syncthreads();
    #pragma unroll
    for (int i = 0; i < 11; i++) {
        float s = acc[i];
        #pragma unroll
        for (int off = 32; off > 0; off >>= 1)
            s += __shfl_down(s, off, 64);
        if (lane == 0) red[wave * 12 + i] = s;
    }
    __syncthreads();
    if (tid < 11)
        Cbuf[blk * 12 + tid] = red[tid] + red[12 + tid] + red[24 + tid] + red[36 + tid];
    if (tid == 11)
        Cbuf[blk * 12 + 11] = mx;
}

// ---------------------------------------------------------------------------
// Kernel 2: combine chunks + fp64 Jacobi with FULLY CONSTANT indices
// (macro-expanded rotations, fixed sweep count, no divergent control flow)
// so A/V live entirely in registers — no scratch. One thread per batch.
// Emits D = R_pred - R_gt (9 floats/batch).
// ---------------------------------------------------------------------------
#define JROT(p, q)                                                          \
    {                                                                       \
        double apq = A[p][q];                                               \
        double theta = (A[q][q] - A[p][p]) / (2.0 * apq);                   \
        double t = copysign(1.0, theta) /                                   \
                   (fabs(theta) + sqrt(theta * theta + 1.0));               \
        t = (fabs(apq) > 0.0) ? t : 0.0;  /* zero pivot -> identity */      \
        double cth = 1.0 / sqrt(t * t + 1.0);                               \
        double sth = t * cth;                                               \
        _Pragma("unroll")                                                   \
        for (int i = 0; i < 4; i++) {                                       \
            double aip = A[i][p], aiq = A[i][q];                            \
            A[i][p] = cth * aip - sth * aiq;                                \
            A[i][q] = sth * aip + cth * aiq;                                \
        }                                                                   \
        _Pragma("unroll")                                                   \
        for (int i = 0; i < 4; i++) {                                       \
            double api = A[p][i], aqi = A[q][i];                            \
            A[p][i] = cth * api - sth * aqi;                                \
            A[q][i] = sth * api + cth * aqi;                                \
        }                                                                   \
        _Pragma("unroll")                                                   \
        for (int i = 0; i < 4; i++) {                                       \
            double vip = V[i][p], viq = V[i][q];                            \
            V[i][p] = cth * vip - sth * viq;                                \
            V[i][q] = sth * vip + cth * viq;                                \
        }                                                                   \
    }

__global__ __launch_bounds__(64) void k_eig(
    const float* __restrict__ Cbuf, const float* __restrict__ gt,
    float* __restrict__ Dbuf)
{
    int b = blockIdx.x * 64 + threadIdx.x;
    if (b >= BATCH) return;
    const float* C = Cbuf + b * 48;

    float mg = fmaxf(fmaxf(C[11], C[23]), fmaxf(C[35], C[47]));
    double sum_e = 0.0;
    double M[10];
    #pragma unroll
    for (int i = 0; i < 10; i++) M[i] = 0.0;
    #pragma unroll
    for (int c = 0; c < 4; c++) {
        const float* cc = C + c * 12;
        double f = exp((double)(cc[11] - mg));
        sum_e += f * (double)cc[0];
        #pragma unroll
        for (int i = 0; i < 10; i++) M[i] += f * (double)cc[1 + i];
    }
    double inv = 1.0 / sum_e;

    double A[4][4], V[4][4];
    A[0][0] = M[0]*inv; A[0][1] = M[1]*inv; A[0][2] = M[2]*inv; A[0][3] = M[3]*inv;
    A[1][1] = M[4]*inv; A[1][2] = M[5]*inv; A[1][3] = M[6]*inv;
    A[2][2] = M[7]*inv; A[2][3] = M[8]*inv; A[3][3] = M[9]*inv;
    A[1][0] = A[0][1]; A[2][0] = A[0][2]; A[3][0] = A[0][3];
    A[2][1] = A[1][2]; A[3][1] = A[1][3]; A[3][2] = A[2][3];
    #pragma unroll
    for (int i = 0; i < 4; i++)
        #pragma unroll
        for (int j = 0; j < 4; j++) V[i][j] = (i == j) ? 1.0 : 0.0;

    #pragma unroll
    for (int sweep = 0; sweep < 6; ++sweep) {
        JROT(0, 1) JROT(0, 2) JROT(0, 3) JROT(1, 2) JROT(1, 3) JROT(2, 3)
    }

    // argmax eigenvalue -> eigenvector column, branch-free selects
    double d0 = A[0][0], d1 = A[1][1], d2 = A[2][2], d3 = A[3][3];
    double qr, qi, qj, qk, bestv;
    bestv = d0; qr = V[0][0]; qi = V[1][0]; qj = V[2][0]; qk = V[3][0];
    if (d1 > bestv) { bestv = d1; qr = V[0][1]; qi = V[1][1]; qj = V[2][1]; qk = V[3][1]; }
    if (d2 > bestv) { bestv = d2; qr = V[0][2]; qi = V[1][2]; qj = V[2][2]; qk = V[3][2]; }
    if (d3 > bestv) { bestv = d3; qr = V[0][3]; qi = V[1][3]; qj = V[2][3]; qk = V[3][3]; }
    double ps = 2.0 / (qr*qr + qi*qi + qj*qj + qk*qk);

    double gr = gt[b*4+0], gi = gt[b*4+1], gj = gt[b*4+2], gk = gt[b*4+3];
    double gs = 2.0 / (gr*gr + gi*gi + gj*gj + gk*gk);

    float* D = Dbuf + b * 9;
    D[0] = (float)((1.0 - ps*(qj*qj + qk*qk)) - (1.0 - gs*(gj*gj + gk*gk)));
    D[1] = (float)((ps*(qi*qj - qk*qr))       - (gs*(gi*gj - gk*gr)));
    D[2] = (float)((ps*(qi*qk + qj*qr))       - (gs*(gi*gk + gj*gr)));
    D[3] = (float)((ps*(qi*qj + qk*qr))       - (gs*(gi*gj + gk*gr)));
    D[4] = (float)((1.0 - ps*(qi*qi + qk*qk)) - (1.0 - gs*(gi*gi + gk*gk)));
    D[5] = (float)((ps*(qj*qk - qi*qr))       - (gs*(gj*gk - gi*gr)));
    D[6] = (float)((ps*(qi*qk - qj*qr))       - (gs*(gi*gk - gj*gr)));
    D[7] = (float)((ps*(qj*qk + qi*qr))       - (gs*(gj*gk + gi*gr)));
    D[8] = (float)((1.0 - ps*(qi*qi + qj*qj)) - (1.0 - gs*(gi*gi + gj*gj)));
}

// ---------------------------------------------------------------------------
// Kernel 3: ||p . D|| per point, accumulate per block.
// ---------------------------------------------------------------------------
__global__ __launch_bounds__(256) void k_points(
    const float* __restrict__ point, const float* __restrict__ Dbuf,
    float* __restrict__ partial)
{
    const int blk   = blockIdx.x;
    const int b     = blk >> 2;
    const int chunk = blk & 3;
    const int tid   = threadIdx.x;
    const int lane  = tid & 63, wave = tid >> 6;
    __shared__ float red[4];

    const float* Dp = Dbuf + b * 9;
    float d[9];
    #pragma unroll
    for (int i = 0; i < 9; i++) d[i] = Dp[i];

    const float4* base = (const float4*)(point + ((size_t)b * PDIM + chunk * 1024) * 3);
    float4 v0 = base[tid * 3 + 0];
    float4 v1 = base[tid * 3 + 1];
    float4 v2 = base[tid * 3 + 2];
    float px[4] = { v0.x, v0.w, v1.z, v2.y };
    float py[4] = { v0.y, v1.x, v1.w, v2.z };
    float pz[4] = { v0.z, v1.y, v2.x, v2.w };

    float sum = 0.f;
    #pragma unroll
    for (int t = 0; t < 4; t++) {
        float x = px[t], y = py[t], z = pz[t];
        float dx = x*d[0] + y*d[3] + z*d[6];
        float dy = x*d[1] + y*d[4] + z*d[7];
        float dz = x*d[2] + y*d[5] + z*d[8];
        sum += sqrtf(dx*dx + dy*dy + dz*dz);
    }
    #pragma unroll
    for (int off = 32; off > 0; off >>= 1)
        sum += __shfl_down(sum, off, 64);
    if (lane == 0) red[wave] = sum;
    __syncthreads();
    if (tid == 0) partial[blk] = red[0] + red[1] + red[2] + red[3];
}

// ---------------------------------------------------------------------------
// Kernel 4: reduce 2048 partials in fp64, write mean.
// ---------------------------------------------------------------------------
__global__ __launch_bounds__(256) void k_final(
    const float* __restrict__ partial, float* __restrict__ out)
{
    const int tid  = threadIdx.x;
    const int lane = tid & 63, wave = tid >> 6;
    __shared__ double red[4];
    double s = 0.0;
    for (int i = tid; i < 2048; i += 256) s += (double)partial[i];
    #pragma unroll
    for (int off = 32; off > 0; off >>= 1)
        s += __shfl_down(s, off, 64);
    if (lane == 0) red[wave] = s;
    __syncthreads();
    if (tid == 0)
        out[0] = (float)((red[0] + red[1] + red[2] + red[3]) /
                         (double)((size_t)BATCH * PDIM));
}

extern "C" void kernel_launch(void* const* d_in, const int* in_sizes, int n_in,
                              void* d_out, int out_size, void* d_ws, size_t ws_size,
                              hipStream_t stream)
{
    const float* sep   = (const float*)d_in[0];   // (512, 8192)
    const float* ohm   = (const float*)d_in[1];   // (512, 8192, 4)
    const float* gt    = (const float*)d_in[2];   // (512, 4)
    const float* point = (const float*)d_in[3];   // (512, 4096, 3)
    float* out = (float*)d_out;

    float* Cbuf = (float*)d_ws;                 // 2048*12 floats
    float* Dbuf = Cbuf + BATCH * 4 * 12;        // 512*9 floats
    float* Pbuf = Dbuf + BATCH * 9;             // 2048 floats

    k_partial<<<BATCH * 4, 256, 0, stream>>>(sep, ohm, Cbuf);
    k_eig<<<8, 64, 0, stream>>>(Cbuf, gt, Dbuf);
    k_points<<<2048, 256, 0, stream>>>(point, Dbuf, Pbuf);
    k_final<<<1, 256, 0, stream>>>(Pbuf, out);
}

// Round 4
// 149.683 us; speedup vs baseline: 1.1195x; 1.0002x over previous
//
#include <hip/hip_runtime.h>
#include <math.h>

#define KDIM 8192
#define BATCH 512
#define PDIM 4096
#define CHUNK 2048      // k-entries per block in stage 1 (4 chunks per batch)

// ---------------------------------------------------------------------------
// Kernel 1: flash-style partial softmax-weighted outer-product accumulation.
// Grid: BATCH*4 blocks x 256 threads. Block (b, c) handles k in [c*2048, ...).
// Writes 12 floats per chunk: [sum_e, A00..A33 (10 upper-tri), mx]
// using the CHUNK-LOCAL max as the softmax shift (rescaled at combine time).
// ---------------------------------------------------------------------------
__global__ __launch_bounds__(256) void k_partial(
    const float* __restrict__ sep, const float* __restrict__ ohm,
    float* __restrict__ Cbuf)
{
    __shared__ float ss[CHUNK];   // 8 KB
    __shared__ float red[64];
    const int blk  = blockIdx.x;
    const int b    = blk >> 2;
    const int c    = blk & 3;
    const int tid  = threadIdx.x;
    const int lane = tid & 63, wave = tid >> 6;

    const float4* s4  = (const float4*)(sep + (size_t)b * KDIM + c * CHUNK);
    float4*       ss4 = (float4*)ss;
    float mx = -INFINITY;
    #pragma unroll
    for (int i = 0; i < CHUNK / 4 / 256; i++) {
        float4 v = s4[tid + i * 256];
        ss4[tid + i * 256] = v;
        mx = fmaxf(mx, fmaxf(fmaxf(v.x, v.y), fmaxf(v.z, v.w)));
    }
    #pragma unroll
    for (int off = 32; off > 0; off >>= 1)
        mx = fmaxf(mx, __shfl_down(mx, off, 64));
    if (lane == 0) red[wave] = mx;
    __syncthreads();
    mx = fmaxf(fmaxf(red[0], red[1]), fmaxf(red[2], red[3]));

    float acc[11];
    #pragma unroll
    for (int i = 0; i < 11; i++) acc[i] = 0.f;

    const float4* q4 = (const float4*)(ohm + ((size_t)b * KDIM + c * CHUNK) * 4);
    #pragma unroll
    for (int j = 0; j < CHUNK / 256; j++) {
        const int k = j * 256 + tid;
        float4 q = q4[k];
        float e  = __expf(ss[k] - mx);
        float ex = e * q.x, ey = e * q.y, ez = e * q.z, ew = e * q.w;
        acc[0]  += e;
        acc[1]  += ex * q.x; acc[2] += ex * q.y; acc[3] += ex * q.z; acc[4] += ex * q.w;
        acc[5]  += ey * q.y; acc[6] += ey * q.z; acc[7] += ey * q.w;
        acc[8]  += ez * q.z; acc[9] += ez * q.w;
        acc[10] += ew * q.w;
    }

    __syncthreads();
    #pragma unroll
    for (int i = 0; i < 11; i++) {
        float s = acc[i];
        #pragma unroll
        for (int off = 32; off > 0; off >>= 1)
            s += __shfl_down(s, off, 64);
        if (lane == 0) red[wave * 12 + i] = s;
    }
    __syncthreads();
    if (tid < 11)
        Cbuf[blk * 12 + tid] = red[tid] + red[12 + tid] + red[24 + tid] + red[36 + tid];
    if (tid == 11)
        Cbuf[blk * 12 + 11] = mx;
}

// ---------------------------------------------------------------------------
// Kernel 2: combine chunks + fp32 Jacobi on EXPLICIT SCALARS (no arrays ->
// no scratch possible). Symmetric storage: 10 unique A entries + 16 V entries.
// One thread per batch; emits D = R_pred - R_gt (9 floats/batch).
// ---------------------------------------------------------------------------
// Pivot (p,q), other indices (r,s). APP/AQQ/APQ: pivot entries. ARP=a[r][p],
// ARQ=a[r][q], ASP=a[s][p], ASQ=a[s][q] (symmetric, sorted names).
// VPi=v[i][p], VQi=v[i][q].
#define ROT(APP, AQQ, APQ, ARP, ARQ, ASP, ASQ,                              \
            VP0, VQ0, VP1, VQ1, VP2, VQ2, VP3, VQ3)                         \
    {                                                                       \
        float apq = APQ;                                                    \
        float theta = (AQQ - APP) / (2.0f * apq);                           \
        float t = copysignf(1.0f, theta) /                                  \
                  (fabsf(theta) + sqrtf(theta * theta + 1.0f));             \
        t = (fabsf(apq) > 0.0f) ? t : 0.0f;                                 \
        float c = 1.0f / sqrtf(t * t + 1.0f);                               \
        float s = t * c;                                                    \
        float app = APP, aqq = AQQ;                                         \
        APP = c*c*app - 2.0f*s*c*apq + s*s*aqq;                             \
        AQQ = s*s*app + 2.0f*s*c*apq + c*c*aqq;                             \
        APQ = 0.0f;                                                         \
        float x;                                                            \
        x = ARP; ARP = c*x - s*ARQ; ARQ = s*x + c*ARQ;                      \
        x = ASP; ASP = c*x - s*ASQ; ASQ = s*x + c*ASQ;                      \
        x = VP0; VP0 = c*x - s*VQ0; VQ0 = s*x + c*VQ0;                      \
        x = VP1; VP1 = c*x - s*VQ1; VQ1 = s*x + c*VQ1;                      \
        x = VP2; VP2 = c*x - s*VQ2; VQ2 = s*x + c*VQ2;                      \
        x = VP3; VP3 = c*x - s*VQ3; VQ3 = s*x + c*VQ3;                      \
    }

__global__ __launch_bounds__(64, 1) void k_eig(
    const float* __restrict__ Cbuf, const float* __restrict__ gt,
    float* __restrict__ Dbuf)
{
    int b = blockIdx.x * 64 + threadIdx.x;
    if (b >= BATCH) return;
    const float* C = Cbuf + b * 48;

    // flash-combine the 4 chunks (normalization constant cancels in eigvecs)
    float mg = fmaxf(fmaxf(C[11], C[23]), fmaxf(C[35], C[47]));
    float f0 = __expf(C[11] - mg), f1 = __expf(C[23] - mg);
    float f2 = __expf(C[35] - mg), f3 = __expf(C[47] - mg);
    float inv = 1.0f / (f0*C[0] + f1*C[12] + f2*C[24] + f3*C[36]);
    #define CMB(i) ((f0*C[1+(i)] + f1*C[13+(i)] + f2*C[25+(i)] + f3*C[37+(i)]) * inv)
    float a00 = CMB(0), a01 = CMB(1), a02 = CMB(2), a03 = CMB(3);
    float a11 = CMB(4), a12 = CMB(5), a13 = CMB(6);
    float a22 = CMB(7), a23 = CMB(8), a33 = CMB(9);
    #undef CMB

    float v00 = 1.f, v01 = 0.f, v02 = 0.f, v03 = 0.f;
    float v10 = 0.f, v11 = 1.f, v12 = 0.f, v13 = 0.f;
    float v20 = 0.f, v21 = 0.f, v22 = 1.f, v23 = 0.f;
    float v30 = 0.f, v31 = 0.f, v32 = 0.f, v33 = 1.f;

    #pragma unroll
    for (int sweep = 0; sweep < 8; ++sweep) {
        // (p,q)=(0,1), others 2,3
        ROT(a00, a11, a01, a02, a12, a03, a13,
            v00, v01, v10, v11, v20, v21, v30, v31)
        // (0,2), others 1,3
        ROT(a00, a22, a02, a01, a12, a03, a23,
            v00, v02, v10, v12, v20, v22, v30, v32)
        // (0,3), others 1,2
        ROT(a00, a33, a03, a01, a13, a02, a23,
            v00, v03, v10, v13, v20, v23, v30, v33)
        // (1,2), others 0,3
        ROT(a11, a22, a12, a01, a02, a13, a23,
            v01, v02, v11, v12, v21, v22, v31, v32)
        // (1,3), others 0,2
        ROT(a11, a33, a13, a01, a03, a12, a23,
            v01, v03, v11, v13, v21, v23, v31, v33)
        // (2,3), others 0,1
        ROT(a22, a33, a23, a02, a03, a12, a13,
            v02, v03, v12, v13, v22, v23, v32, v33)
    }

    // argmax eigenvalue -> eigenvector column (branch-free selects)
    float qr, qi, qj, qk, bestv;
    bestv = a00; qr = v00; qi = v10; qj = v20; qk = v30;
    if (a11 > bestv) { bestv = a11; qr = v01; qi = v11; qj = v21; qk = v31; }
    if (a22 > bestv) { bestv = a22; qr = v02; qi = v12; qj = v22; qk = v32; }
    if (a33 > bestv) { bestv = a33; qr = v03; qi = v13; qj = v23; qk = v33; }
    float ps = 2.0f / (qr*qr + qi*qi + qj*qj + qk*qk);

    float gr = gt[b*4+0], gi = gt[b*4+1], gj = gt[b*4+2], gk = gt[b*4+3];
    float gs = 2.0f / (gr*gr + gi*gi + gj*gj + gk*gk);

    // D = R_pred - R_gt, row-major (eigenvector sign irrelevant: even in q)
    float* D = Dbuf + b * 9;
    D[0] = (1.0f - ps*(qj*qj + qk*qk)) - (1.0f - gs*(gj*gj + gk*gk));
    D[1] = (ps*(qi*qj - qk*qr))        - (gs*(gi*gj - gk*gr));
    D[2] = (ps*(qi*qk + qj*qr))        - (gs*(gi*gk + gj*gr));
    D[3] = (ps*(qi*qj + qk*qr))        - (gs*(gi*gj + gk*gr));
    D[4] = (1.0f - ps*(qi*qi + qk*qk)) - (1.0f - gs*(gi*gi + gk*gk));
    D[5] = (ps*(qj*qk - qi*qr))        - (gs*(gj*gk - gi*gr));
    D[6] = (ps*(qi*qk - qj*qr))        - (gs*(gi*gk - gj*gr));
    D[7] = (ps*(qj*qk + qi*qr))        - (gs*(gj*gk + gi*gr));
    D[8] = (1.0f - ps*(qi*qi + qj*qj)) - (1.0f - gs*(gi*gi + gj*gj));
}

// ---------------------------------------------------------------------------
// Kernel 3: ||p . D|| per point, accumulate per block.
// ---------------------------------------------------------------------------
__global__ __launch_bounds__(256) void k_points(
    const float* __restrict__ point, const float* __restrict__ Dbuf,
    float* __restrict__ partial)
{
    const int blk   = blockIdx.x;
    const int b     = blk >> 2;
    const int chunk = blk & 3;
    const int tid   = threadIdx.x;
    const int lane  = tid & 63, wave = tid >> 6;
    __shared__ float red[4];

    const float* Dp = Dbuf + b * 9;
    float d[9];
    #pragma unroll
    for (int i = 0; i < 9; i++) d[i] = Dp[i];

    const float4* base = (const float4*)(point + ((size_t)b * PDIM + chunk * 1024) * 3);
    float4 v0 = base[tid * 3 + 0];
    float4 v1 = base[tid * 3 + 1];
    float4 v2 = base[tid * 3 + 2];
    float px[4] = { v0.x, v0.w, v1.z, v2.y };
    float py[4] = { v0.y, v1.x, v1.w, v2.z };
    float pz[4] = { v0.z, v1.y, v2.x, v2.w };

    float sum = 0.f;
    #pragma unroll
    for (int t = 0; t < 4; t++) {
        float x = px[t], y = py[t], z = pz[t];
        float dx = x*d[0] + y*d[3] + z*d[6];
        float dy = x*d[1] + y*d[4] + z*d[7];
        float dz = x*d[2] + y*d[5] + z*d[8];
        sum += sqrtf(dx*dx + dy*dy + dz*dz);
    }
    #pragma unroll
    for (int off = 32; off > 0; off >>= 1)
        sum += __shfl_down(sum, off, 64);
    if (lane == 0) red[wave] = sum;
    __syncthreads();
    if (tid == 0) partial[blk] = red[0] + red[1] + red[2] + red[3];
}

// ---------------------------------------------------------------------------
// Kernel 4: reduce 2048 partials in fp64, write mean.
// ---------------------------------------------------------------------------
__global__ __launch_bounds__(256) void k_final(
    const float* __restrict__ partial, float* __restrict__ out)
{
    const int tid  = threadIdx.x;
    const int lane = tid & 63, wave = tid >> 6;
    __shared__ double red[4];
    double s = 0.0;
    for (int i = tid; i < 2048; i += 256) s += (double)partial[i];
    #pragma unroll
    for (int off = 32; off > 0; off >>= 1)
        s += __shfl_down(s, off, 64);
    if (lane == 0) red[wave] = s;
    __syncthreads();
    if (tid == 0)
        out[0] = (float)((red[0] + red[1] + red[2] + red[3]) /
                         (double)((size_t)BATCH * PDIM));
}

extern "C" void kernel_launch(void* const* d_in, const int* in_sizes, int n_in,
                              void* d_out, int out_size, void* d_ws, size_t ws_size,
                              hipStream_t stream)
{
    const float* sep   = (const float*)d_in[0];   // (512, 8192)
    const float* ohm   = (const float*)d_in[1];   // (512, 8192, 4)
    const float* gt    = (const float*)d_in[2];   // (512, 4)
    const float* point = (const float*)d_in[3];   // (512, 4096, 3)
    float* out = (float*)d_out;

    float* Cbuf = (float*)d_ws;                 // 2048*12 floats
    float* Dbuf = Cbuf + BATCH * 4 * 12;        // 512*9 floats
    float* Pbuf = Dbuf + BATCH * 9;             // 2048 floats

    k_partial<<<BATCH * 4, 256, 0, stream>>>(sep, ohm, Cbuf);
    k_eig<<<8, 64, 0, stream>>>(Cbuf, gt, Dbuf);
    k_points<<<2048, 256, 0, stream>>>(point, Dbuf, Pbuf);
    k_final<<<1, 256, 0, stream>>>(Pbuf, out);
}